// Round 1
// baseline (501.116 us; speedup 1.0000x reference)
//
#include <hip/hip_runtime.h>
#include <stdint.h>

#define B_ 128
#define T_ 1024
#define H_ 512
#define A_ 256
#define G_ 2128

typedef short s16x8 __attribute__((ext_vector_type(8)));
typedef float f32x4 __attribute__((ext_vector_type(4)));
typedef unsigned int u32;

__device__ inline unsigned short f2bf(float f) {
  unsigned u = __float_as_uint(f);
  u += 0x7fff + ((u >> 16) & 1);   // round-to-nearest-even
  return (unsigned short)(u >> 16);
}
__device__ inline unsigned pack2bf(float a, float b) {
  return ((unsigned)f2bf(b) << 16) | f2bf(a);
}
__device__ inline float bf_lo(unsigned u) { return __uint_as_float(u << 16); }
__device__ inline float bf_hi(unsigned u) { return __uint_as_float(u & 0xffff0000u); }
__device__ inline float fast_tanh(float x) {
  x = fminf(15.f, fmaxf(-15.f, x));
  float e = __expf(2.f * x);
  return (e - 1.f) * __builtin_amdgcn_rcpf(e + 1.f);
}
// async global->LDS, 16B per lane; LDS dest = uniform base + lane*16
__device__ inline void gl_lds16(const void* g, void* l) {
  __builtin_amdgcn_global_load_lds(
      (const __attribute__((address_space(1))) u32*)g,
      (__attribute__((address_space(3))) u32*)l, 16, 0, 0);
}

// K^T bf16 tiled [kb][a][k'], 16B-group swizzle baked: group g of row a at g^(a&3).
__global__ void prep_kt(const float* __restrict__ K,
                        unsigned short* __restrict__ khi) {
  int idx = blockIdx.x * 256 + threadIdx.x;   // h*256 + a
  int h = idx >> 8;
  int a = idx & 255;
  int kb = h >> 5, k = h & 31;
  int grp = k >> 3, sub = k & 7;
  khi[kb * 8192 + a * 32 + ((grp ^ (a & 3)) * 8) + sub] = f2bf(K[idx]);
}

// gp4[gc][b][a] = partial of w0 * sum_g genes[b,g]*Wg[g,a]; gc==0 adds biases.
__global__ __launch_bounds__(256) void gene_proj_k(
    const float* __restrict__ genes, const float* __restrict__ w0p,
    const float* __restrict__ Wg, const float* __restrict__ bg,
    const float* __restrict__ db, float* __restrict__ gp4) {
  __shared__ float sg[532];
  int b = blockIdx.x;
  int gc = blockIdx.y;          // 0..3 chunks of 532
  int a = threadIdx.x;
  int g0 = gc * 532;
  for (int i = threadIdx.x; i < 532; i += 256) sg[i] = genes[(size_t)b * G_ + g0 + i];
  __syncthreads();
  float s = 0.f;
  #pragma unroll 8
  for (int g = 0; g < 532; ++g)
    s = fmaf(sg[g], Wg[(size_t)(g0 + g) * A_ + a], s);
  float val = w0p[0] * s;
  if (gc == 0) val += bg[a] + db[a];
  gp4[(gc * B_ + b) * A_ + a] = val;
}

// Pass 1 (fused convert + GEMM): block = 128 t x 256 a, 4 waves.
// Wave w: 8 i-frags (t) x 4 j-frags (a in [w*64,w*64+64)) = 32 MFMA / K-step.
// A: fp32 smiles read coalesced, bf16-packed in-register, stored to LDS
// (swizzled) AND to global smb (tile-major, for pass3). B: global_load_lds.
__global__ __launch_bounds__(256, 2) void pass1(
    const float* __restrict__ smiles, const unsigned short* __restrict__ khi,
    unsigned short* __restrict__ smb, const float* __restrict__ gp4,
    const float* __restrict__ v, float* __restrict__ xv) {
  __shared__ unsigned short sA[128 * 32];   // 8 KB
  __shared__ unsigned short sB[256 * 32];   // 16 KB
  __shared__ float sXV[128 * 4];            // 2 KB

  const int tid = threadIdx.x;
  const int b = blockIdx.y;
  const int tb = blockIdx.x;                // 0..7 (128-t tiles)
  const int lane = tid & 63;
  const int w = tid >> 6;
  const int n = lane & 15;
  const int q = lane >> 4;

  // A staging: thread -> row ar (0..127), half-row (16 fp32)
  const int ar = tid >> 1;
  const int half = tid & 1;
  const int g0 = half * 2;                  // groups {0,1} or {2,3}
  const int s0 = (g0 ^ (ar & 3)) * 8;
  const int s1 = ((g0 + 1) ^ (ar & 3)) * 8;
  const float* asrc = smiles + ((size_t)(b * 1024 + tb * 128 + ar)) * 512 + half * 16;
  unsigned short* adst = smb + (((size_t)(b * 8 + tb)) * 16) * 4096 + ar * 32;

  f32x4 acc[8][4];
  #pragma unroll
  for (int i = 0; i < 8; ++i)
    #pragma unroll
    for (int j = 0; j < 4; ++j)
      acc[i][j] = (f32x4){0.f, 0.f, 0.f, 0.f};

  float4 f0 = *reinterpret_cast<const float4*>(asrc);
  float4 f1 = *reinterpret_cast<const float4*>(asrc + 4);
  float4 f2 = *reinterpret_cast<const float4*>(asrc + 8);
  float4 f3 = *reinterpret_cast<const float4*>(asrc + 12);

  for (int kb = 0; kb < 16; ++kb) {
    __syncthreads();
    // stage A (in regs) to LDS + keep bf16 copy in global for pass3
    uint4 p0, p1;
    p0.x = pack2bf(f0.x, f0.y); p0.y = pack2bf(f0.z, f0.w);
    p0.z = pack2bf(f1.x, f1.y); p0.w = pack2bf(f1.z, f1.w);
    p1.x = pack2bf(f2.x, f2.y); p1.y = pack2bf(f2.z, f2.w);
    p1.z = pack2bf(f3.x, f3.y); p1.w = pack2bf(f3.z, f3.w);
    *reinterpret_cast<uint4*>(&sA[ar * 32 + s0]) = p0;
    *reinterpret_cast<uint4*>(&sA[ar * 32 + s1]) = p1;
    *reinterpret_cast<uint4*>(adst + kb * 4096 + s0) = p0;
    *reinterpret_cast<uint4*>(adst + kb * 4096 + s1) = p1;
    // stage B: wave w fills sB[w*2048 .. +2048)
    #pragma unroll
    for (int r = 0; r < 4; ++r)
      gl_lds16(khi + kb * 8192 + w * 2048 + r * 512 + lane * 8,
               &sB[w * 2048 + r * 512]);
    __syncthreads();
    // prefetch next A chunk (hides under MFMAs)
    if (kb < 15) {
      f0 = *reinterpret_cast<const float4*>(asrc + (kb + 1) * 32);
      f1 = *reinterpret_cast<const float4*>(asrc + (kb + 1) * 32 + 4);
      f2 = *reinterpret_cast<const float4*>(asrc + (kb + 1) * 32 + 8);
      f3 = *reinterpret_cast<const float4*>(asrc + (kb + 1) * 32 + 12);
    }

    s16x8 af[8], bh[4];
    const int sw = (q ^ (n & 3)) * 8;
    #pragma unroll
    for (int j = 0; j < 4; ++j)
      bh[j] = *reinterpret_cast<const s16x8*>(&sB[(w * 64 + j * 16 + n) * 32 + sw]);
    #pragma unroll
    for (int i = 0; i < 8; ++i)
      af[i] = *reinterpret_cast<const s16x8*>(&sA[(i * 16 + n) * 32 + sw]);
    #pragma unroll
    for (int i = 0; i < 8; ++i)
      #pragma unroll
      for (int j = 0; j < 4; ++j)
        acc[i][j] = __builtin_amdgcn_mfma_f32_16x16x32_bf16(af[i], bh[j], acc[i][j], 0, 0, 0);
  }

  // epilogue: sum_a v_a * tanh(gp + proj); D: t = q*4+r (+16i), a = n (+16j+64w)
  float vv[4], gg[4];
  #pragma unroll
  for (int j = 0; j < 4; ++j) {
    int a = w * 64 + j * 16 + n;
    int idx = b * A_ + a;
    vv[j] = v[a];
    gg[j] = gp4[idx] + gp4[B_ * A_ + idx] + gp4[2 * B_ * A_ + idx] +
            gp4[3 * B_ * A_ + idx];
  }
  #pragma unroll
  for (int i = 0; i < 8; ++i) {
    #pragma unroll
    for (int r = 0; r < 4; ++r) {
      float s = 0.f;
      #pragma unroll
      for (int j = 0; j < 4; ++j)
        s += vv[j] * fast_tanh(acc[i][j][r] + gg[j]);
      s += __shfl_xor(s, 1); s += __shfl_xor(s, 2);
      s += __shfl_xor(s, 4); s += __shfl_xor(s, 8);
      if (n == 0) sXV[(i * 16 + q * 4 + r) * 4 + w] = s;
    }
  }
  __syncthreads();
  if (tid < 128) {
    float* p = &sXV[tid * 4];
    xv[(size_t)b * T_ + tb * 128 + tid] = p[0] + p[1] + p[2] + p[3];
  }
}

__global__ __launch_bounds__(256) void softmax_k(const float* __restrict__ xv,
                                                 float* __restrict__ alphas) {
  __shared__ float red[8];
  int b = blockIdx.x, tid = threadIdx.x;
  float4 x = *reinterpret_cast<const float4*>(xv + b * T_ + tid * 4);
  float m = fmaxf(fmaxf(x.x, x.y), fmaxf(x.z, x.w));
  #pragma unroll
  for (int o = 1; o < 64; o <<= 1) m = fmaxf(m, __shfl_xor(m, o));
  if ((tid & 63) == 0) red[tid >> 6] = m;
  __syncthreads();
  m = fmaxf(fmaxf(red[0], red[1]), fmaxf(red[2], red[3]));
  float e0 = __expf(x.x - m), e1 = __expf(x.y - m);
  float e2 = __expf(x.z - m), e3 = __expf(x.w - m);
  float s = e0 + e1 + e2 + e3;
  #pragma unroll
  for (int o = 1; o < 64; o <<= 1) s += __shfl_xor(s, o);
  if ((tid & 63) == 0) red[4 + (tid >> 6)] = s;
  __syncthreads();
  s = red[4] + red[5] + red[6] + red[7];
  float inv = 1.f / s;
  float4 o4;
  o4.x = e0 * inv; o4.y = e1 * inv; o4.z = e2 * inv; o4.w = e3 * inv;
  *reinterpret_cast<float4*>(alphas + b * T_ + tid * 4) = o4;
}

// out[b,h] = sum_t smiles_bf16[b,t,h] * alphas[b,t], tiled layout
// [b][tb(8)][kb(16)][tp(128)][32 shorts swizzled].
__global__ __launch_bounds__(256) void pass3(const unsigned short* __restrict__ smb,
                                             const float* __restrict__ alphas,
                                             float* __restrict__ out) {
  __shared__ float red[3][64][8];     // 6 KB
  int b = blockIdx.y, ts = blockIdx.x;
  int tid = threadIdx.x;
  int hg = tid & 63, tq = tid >> 6;
  int kb = hg >> 2, g = hg & 3;
  float acc[8] = {0.f, 0.f, 0.f, 0.f, 0.f, 0.f, 0.f, 0.f};
  for (int tb = ts * 2; tb < ts * 2 + 2; ++tb) {
    const unsigned short* tile = smb + (((size_t)b * 8 + tb) * 16 + kb) * 4096;
    const float* al = alphas + b * T_ + tb * 128;
    #pragma unroll 4
    for (int tt = 0; tt < 32; ++tt) {
      int tp = tq * 32 + tt;
      float a = al[tp];
      uint4 d = *reinterpret_cast<const uint4*>(tile + tp * 32 + ((g ^ (tp & 3)) * 8));
      acc[0] = fmaf(a, bf_lo(d.x), acc[0]); acc[1] = fmaf(a, bf_hi(d.x), acc[1]);
      acc[2] = fmaf(a, bf_lo(d.y), acc[2]); acc[3] = fmaf(a, bf_hi(d.y), acc[3]);
      acc[4] = fmaf(a, bf_lo(d.z), acc[4]); acc[5] = fmaf(a, bf_hi(d.z), acc[5]);
      acc[6] = fmaf(a, bf_lo(d.w), acc[6]); acc[7] = fmaf(a, bf_hi(d.w), acc[7]);
    }
  }
  if (tq) {
    #pragma unroll
    for (int e = 0; e < 8; ++e) red[tq - 1][hg][e] = acc[e];
  }
  __syncthreads();
  if (tq == 0) {
    float* op = out + (size_t)b * H_ + kb * 32 + g * 8;
    #pragma unroll
    for (int e = 0; e < 8; ++e)
      atomicAdd(op + e, acc[e] + red[0][hg][e] + red[1][hg][e] + red[2][hg][e]);
  }
}

extern "C" void kernel_launch(void* const* d_in, const int* in_sizes, int n_in,
                              void* d_out, int out_size, void* d_ws, size_t ws_size,
                              hipStream_t stream) {
  const float* genes  = (const float*)d_in[0];
  const float* smiles = (const float*)d_in[1];
  const float* w0     = (const float*)d_in[2];
  const float* wg     = (const float*)d_in[3];
  const float* bg     = (const float*)d_in[4];
  const float* dk     = (const float*)d_in[5];
  const float* db     = (const float*)d_in[6];
  const float* v      = (const float*)d_in[7];
  float* out = (float*)d_out;            // [B,H] output then [B,T] alphas
  char* ws = (char*)d_ws;
  float* gp4 = (float*)ws;                                   // 512 KB (4 partials)
  unsigned short* khi = (unsigned short*)(ws + 524288);      // 256 KB
  float* xv = (float*)(ws + 524288 + 262144);                // 512 KB
  unsigned short* smb = (unsigned short*)(ws + (2 << 20));   // 128 MB
  float* alphas = out + B_ * H_;

  hipMemsetAsync(out, 0, B_ * H_ * sizeof(float), stream);
  prep_kt<<<512, 256, 0, stream>>>(dk, khi);
  gene_proj_k<<<dim3(B_, 4), 256, 0, stream>>>(genes, w0, wg, bg, db, gp4);
  pass1<<<dim3(8, B_), 256, 0, stream>>>(smiles, khi, smb, gp4, v, xv);
  softmax_k<<<B_, 256, 0, stream>>>(xv, alphas);
  pass3<<<dim3(4, B_), 256, 0, stream>>>(smb, alphas, out);
}

// Round 2
// 499.480 us; speedup vs baseline: 1.0033x; 1.0033x over previous
//
#include <hip/hip_runtime.h>
#include <stdint.h>

#define B_ 128
#define T_ 1024
#define H_ 512
#define A_ 256
#define G_ 2128

typedef short s16x8 __attribute__((ext_vector_type(8)));
typedef float f32x4 __attribute__((ext_vector_type(4)));
typedef unsigned int u32;

__device__ inline unsigned short f2bf(float f) {
  unsigned u = __float_as_uint(f);
  u += 0x7fff + ((u >> 16) & 1);   // round-to-nearest-even
  return (unsigned short)(u >> 16);
}
__device__ inline unsigned pack2bf(float a, float b) {
  return ((unsigned)f2bf(b) << 16) | f2bf(a);
}
__device__ inline float bf_lo(unsigned u) { return __uint_as_float(u << 16); }
__device__ inline float bf_hi(unsigned u) { return __uint_as_float(u & 0xffff0000u); }
__device__ inline float fast_tanh(float x) {
  x = fminf(15.f, fmaxf(-15.f, x));
  float e = __expf(2.f * x);
  return (e - 1.f) * __builtin_amdgcn_rcpf(e + 1.f);
}
// async global->LDS, 16B per lane; LDS dest = uniform base + lane*16
__device__ inline void gl_lds16(const void* g, void* l) {
  __builtin_amdgcn_global_load_lds(
      (const __attribute__((address_space(1))) u32*)g,
      (__attribute__((address_space(3))) u32*)l, 16, 0, 0);
}

// K^T bf16 tiled [kb][a][k'], 16B-group swizzle baked: group g of row a at g^(a&3).
__global__ void prep_kt(const float* __restrict__ K,
                        unsigned short* __restrict__ khi) {
  int idx = blockIdx.x * 256 + threadIdx.x;   // h*256 + a
  int h = idx >> 8;
  int a = idx & 255;
  int kb = h >> 5, k = h & 31;
  int grp = k >> 3, sub = k & 7;
  khi[kb * 8192 + a * 32 + ((grp ^ (a & 3)) * 8) + sub] = f2bf(K[idx]);
}

// gp4[gc][b][a] = partial of w0 * sum_g genes[b,g]*Wg[g,a]; gc==0 adds biases.
__global__ __launch_bounds__(256) void gene_proj_k(
    const float* __restrict__ genes, const float* __restrict__ w0p,
    const float* __restrict__ Wg, const float* __restrict__ bg,
    const float* __restrict__ db, float* __restrict__ gp4) {
  __shared__ float sg[532];
  int b = blockIdx.x;
  int gc = blockIdx.y;          // 0..3 chunks of 532
  int a = threadIdx.x;
  int g0 = gc * 532;
  for (int i = threadIdx.x; i < 532; i += 256) sg[i] = genes[(size_t)b * G_ + g0 + i];
  __syncthreads();
  float s = 0.f;
  #pragma unroll 8
  for (int g = 0; g < 532; ++g)
    s = fmaf(sg[g], Wg[(size_t)(g0 + g) * A_ + a], s);
  float val = w0p[0] * s;
  if (gc == 0) val += bg[a] + db[a];
  gp4[(gc * B_ + b) * A_ + a] = val;
}

// Pass 1 (fused convert + GEMM): block = 128 t x 256 a, 4 waves.
// Wave w: 8 i-frags (t) x 4 j-frags (a in [w*64,w*64+64)) = 32 MFMA / K-step.
// A: fp32 smiles read coalesced, bf16-packed in-register, stored to LDS
// (swizzled) AND to global smb (tile-major, for pass3). B: global_load_lds.
//
// K-loop uses raw s_barrier + counted vmcnt (T4): VMEM issue order per iter is
// pinned [gl_lds16 x4][A-prefetch x4][smb store x2] via sched_barrier(0), so
// "s_waitcnt vmcnt(6)" guarantees the 4 gl_lds16 landed while the HBM stores
// and the prefetch stay in flight across the barrier (they complete under the
// 32-MFMA phase). Prefetch is unconditional (clamped offset) to keep the
// vm-op ledger uniform (10 ops/iter) so vmcnt(6) is exact on every iteration.
__global__ __launch_bounds__(256, 2) void pass1(
    const float* __restrict__ smiles, const unsigned short* __restrict__ khi,
    unsigned short* __restrict__ smb, const float* __restrict__ gp4,
    const float* __restrict__ v, float* __restrict__ xv) {
  __shared__ unsigned short sA[128 * 32];   // 8 KB
  __shared__ unsigned short sB[256 * 32];   // 16 KB
  __shared__ float sXV[128 * 4];            // 2 KB

  const int tid = threadIdx.x;
  const int b = blockIdx.y;
  const int tb = blockIdx.x;                // 0..7 (128-t tiles)
  const int lane = tid & 63;
  const int w = tid >> 6;
  const int n = lane & 15;
  const int q = lane >> 4;

  // A staging: thread -> row ar (0..127), half-row (16 fp32)
  const int ar = tid >> 1;
  const int half = tid & 1;
  const int g0 = half * 2;                  // groups {0,1} or {2,3}
  const int s0 = (g0 ^ (ar & 3)) * 8;
  const int s1 = ((g0 + 1) ^ (ar & 3)) * 8;
  const float* asrc = smiles + ((size_t)(b * 1024 + tb * 128 + ar)) * 512 + half * 16;
  unsigned short* adst = smb + (((size_t)(b * 8 + tb)) * 16) * 4096 + ar * 32;

  f32x4 acc[8][4];
  #pragma unroll
  for (int i = 0; i < 8; ++i)
    #pragma unroll
    for (int j = 0; j < 4; ++j)
      acc[i][j] = (f32x4){0.f, 0.f, 0.f, 0.f};

  float4 f0 = *reinterpret_cast<const float4*>(asrc);
  float4 f1 = *reinterpret_cast<const float4*>(asrc + 4);
  float4 f2 = *reinterpret_cast<const float4*>(asrc + 8);
  float4 f3 = *reinterpret_cast<const float4*>(asrc + 12);

  for (int kb = 0; kb < 16; ++kb) {
    // entry barrier: all waves consumed prev frags -> LDS safe to overwrite
    __builtin_amdgcn_sched_barrier(0);
    __builtin_amdgcn_s_barrier();
    __builtin_amdgcn_sched_barrier(0);

    // pack current A chunk (f regs from prev-iter prefetch)
    uint4 p0, p1;
    p0.x = pack2bf(f0.x, f0.y); p0.y = pack2bf(f0.z, f0.w);
    p0.z = pack2bf(f1.x, f1.y); p0.w = pack2bf(f1.z, f1.w);
    p1.x = pack2bf(f2.x, f2.y); p1.y = pack2bf(f2.z, f2.w);
    p1.z = pack2bf(f3.x, f3.y); p1.w = pack2bf(f3.z, f3.w);
    *reinterpret_cast<uint4*>(&sA[ar * 32 + s0]) = p0;    // ds_write (lgkm)
    *reinterpret_cast<uint4*>(&sA[ar * 32 + s1]) = p1;
    __builtin_amdgcn_sched_barrier(0);
    // vm ops 1-4: B stage
    #pragma unroll
    for (int r = 0; r < 4; ++r)
      gl_lds16(khi + kb * 8192 + w * 2048 + r * 512 + lane * 8,
               &sB[w * 2048 + r * 512]);
    __builtin_amdgcn_sched_barrier(0);
    // vm ops 5-8: prefetch next A chunk (clamped; last iter re-reads chunk 0)
    {
      int noff = (kb < 15) ? (kb + 1) * 32 : 0;
      f0 = *reinterpret_cast<const float4*>(asrc + noff);
      f1 = *reinterpret_cast<const float4*>(asrc + noff + 4);
      f2 = *reinterpret_cast<const float4*>(asrc + noff + 8);
      f3 = *reinterpret_cast<const float4*>(asrc + noff + 12);
    }
    // vm ops 9-10: smb stores (newest -> never drained by the barrier wait)
    *reinterpret_cast<uint4*>(adst + kb * 4096 + s0) = p0;
    *reinterpret_cast<uint4*>(adst + kb * 4096 + s1) = p1;
    // wait: sA ds_writes visible + the 4 gl_lds16 landed; 6 newer vm ops
    // (4 prefetch + 2 stores) stay in flight across the barrier.
    asm volatile("s_waitcnt vmcnt(6) lgkmcnt(0)" ::: "memory");
    __builtin_amdgcn_sched_barrier(0);
    __builtin_amdgcn_s_barrier();
    __builtin_amdgcn_sched_barrier(0);

    s16x8 af[8], bh[4];
    const int sw = (q ^ (n & 3)) * 8;
    #pragma unroll
    for (int j = 0; j < 4; ++j)
      bh[j] = *reinterpret_cast<const s16x8*>(&sB[(w * 64 + j * 16 + n) * 32 + sw]);
    #pragma unroll
    for (int i = 0; i < 8; ++i)
      af[i] = *reinterpret_cast<const s16x8*>(&sA[(i * 16 + n) * 32 + sw]);
    #pragma unroll
    for (int i = 0; i < 8; ++i)
      #pragma unroll
      for (int j = 0; j < 4; ++j)
        acc[i][j] = __builtin_amdgcn_mfma_f32_16x16x32_bf16(af[i], bh[j], acc[i][j], 0, 0, 0);
  }

  // epilogue: sum_a v_a * tanh(gp + proj); D: t = q*4+r (+16i), a = n (+16j+64w)
  float vv[4], gg[4];
  #pragma unroll
  for (int j = 0; j < 4; ++j) {
    int a = w * 64 + j * 16 + n;
    int idx = b * A_ + a;
    vv[j] = v[a];
    gg[j] = gp4[idx] + gp4[B_ * A_ + idx] + gp4[2 * B_ * A_ + idx] +
            gp4[3 * B_ * A_ + idx];
  }
  #pragma unroll
  for (int i = 0; i < 8; ++i) {
    #pragma unroll
    for (int r = 0; r < 4; ++r) {
      float s = 0.f;
      #pragma unroll
      for (int j = 0; j < 4; ++j)
        s += vv[j] * fast_tanh(acc[i][j][r] + gg[j]);
      s += __shfl_xor(s, 1); s += __shfl_xor(s, 2);
      s += __shfl_xor(s, 4); s += __shfl_xor(s, 8);
      if (n == 0) sXV[(i * 16 + q * 4 + r) * 4 + w] = s;
    }
  }
  __syncthreads();
  if (tid < 128) {
    float* p = &sXV[tid * 4];
    xv[(size_t)b * T_ + tb * 128 + tid] = p[0] + p[1] + p[2] + p[3];
  }
}

__global__ __launch_bounds__(256) void softmax_k(const float* __restrict__ xv,
                                                 float* __restrict__ alphas) {
  __shared__ float red[8];
  int b = blockIdx.x, tid = threadIdx.x;
  float4 x = *reinterpret_cast<const float4*>(xv + b * T_ + tid * 4);
  float m = fmaxf(fmaxf(x.x, x.y), fmaxf(x.z, x.w));
  #pragma unroll
  for (int o = 1; o < 64; o <<= 1) m = fmaxf(m, __shfl_xor(m, o));
  if ((tid & 63) == 0) red[tid >> 6] = m;
  __syncthreads();
  m = fmaxf(fmaxf(red[0], red[1]), fmaxf(red[2], red[3]));
  float e0 = __expf(x.x - m), e1 = __expf(x.y - m);
  float e2 = __expf(x.z - m), e3 = __expf(x.w - m);
  float s = e0 + e1 + e2 + e3;
  #pragma unroll
  for (int o = 1; o < 64; o <<= 1) s += __shfl_xor(s, o);
  if ((tid & 63) == 0) red[4 + (tid >> 6)] = s;
  __syncthreads();
  s = red[4] + red[5] + red[6] + red[7];
  float inv = 1.f / s;
  float4 o4;
  o4.x = e0 * inv; o4.y = e1 * inv; o4.z = e2 * inv; o4.w = e3 * inv;
  *reinterpret_cast<float4*>(alphas + b * T_ + tid * 4) = o4;
}

// out[b,h] = sum_t smiles_bf16[b,t,h] * alphas[b,t], tiled layout
// [b][tb(8)][kb(16)][tp(128)][32 shorts swizzled].
__global__ __launch_bounds__(256) void pass3(const unsigned short* __restrict__ smb,
                                             const float* __restrict__ alphas,
                                             float* __restrict__ out) {
  __shared__ float red[3][64][8];     // 6 KB
  int b = blockIdx.y, ts = blockIdx.x;
  int tid = threadIdx.x;
  int hg = tid & 63, tq = tid >> 6;
  int kb = hg >> 2, g = hg & 3;
  float acc[8] = {0.f, 0.f, 0.f, 0.f, 0.f, 0.f, 0.f, 0.f};
  for (int tb = ts * 2; tb < ts * 2 + 2; ++tb) {
    const unsigned short* tile = smb + (((size_t)b * 8 + tb) * 16 + kb) * 4096;
    const float* al = alphas + b * T_ + tb * 128;
    #pragma unroll 4
    for (int tt = 0; tt < 32; ++tt) {
      int tp = tq * 32 + tt;
      float a = al[tp];
      uint4 d = *reinterpret_cast<const uint4*>(tile + tp * 32 + ((g ^ (tp & 3)) * 8));
      acc[0] = fmaf(a, bf_lo(d.x), acc[0]); acc[1] = fmaf(a, bf_hi(d.x), acc[1]);
      acc[2] = fmaf(a, bf_lo(d.y), acc[2]); acc[3] = fmaf(a, bf_hi(d.y), acc[3]);
      acc[4] = fmaf(a, bf_lo(d.z), acc[4]); acc[5] = fmaf(a, bf_hi(d.z), acc[5]);
      acc[6] = fmaf(a, bf_lo(d.w), acc[6]); acc[7] = fmaf(a, bf_hi(d.w), acc[7]);
    }
  }
  if (tq) {
    #pragma unroll
    for (int e = 0; e < 8; ++e) red[tq - 1][hg][e] = acc[e];
  }
  __syncthreads();
  if (tq == 0) {
    float* op = out + (size_t)b * H_ + kb * 32 + g * 8;
    #pragma unroll
    for (int e = 0; e < 8; ++e)
      atomicAdd(op + e, acc[e] + red[0][hg][e] + red[1][hg][e] + red[2][hg][e]);
  }
}

extern "C" void kernel_launch(void* const* d_in, const int* in_sizes, int n_in,
                              void* d_out, int out_size, void* d_ws, size_t ws_size,
                              hipStream_t stream) {
  const float* genes  = (const float*)d_in[0];
  const float* smiles = (const float*)d_in[1];
  const float* w0     = (const float*)d_in[2];
  const float* wg     = (const float*)d_in[3];
  const float* bg     = (const float*)d_in[4];
  const float* dk     = (const float*)d_in[5];
  const float* db     = (const float*)d_in[6];
  const float* v      = (const float*)d_in[7];
  float* out = (float*)d_out;            // [B,H] output then [B,T] alphas
  char* ws = (char*)d_ws;
  float* gp4 = (float*)ws;                                   // 512 KB (4 partials)
  unsigned short* khi = (unsigned short*)(ws + 524288);      // 256 KB
  float* xv = (float*)(ws + 524288 + 262144);                // 512 KB
  unsigned short* smb = (unsigned short*)(ws + (2 << 20));   // 128 MB
  float* alphas = out + B_ * H_;

  hipMemsetAsync(out, 0, B_ * H_ * sizeof(float), stream);
  prep_kt<<<512, 256, 0, stream>>>(dk, khi);
  gene_proj_k<<<dim3(B_, 4), 256, 0, stream>>>(genes, w0, wg, bg, db, gp4);
  pass1<<<dim3(8, B_), 256, 0, stream>>>(smiles, khi, smb, gp4, v, xv);
  softmax_k<<<B_, 256, 0, stream>>>(xv, alphas);
  pass3<<<dim3(4, B_), 256, 0, stream>>>(smb, alphas, out);
}

// Round 3
// 485.925 us; speedup vs baseline: 1.0313x; 1.0279x over previous
//
#include <hip/hip_runtime.h>
#include <stdint.h>

#define B_ 128
#define T_ 1024
#define H_ 512
#define A_ 256
#define G_ 2128

typedef short s16x8 __attribute__((ext_vector_type(8)));
typedef float f32x4 __attribute__((ext_vector_type(4)));
typedef unsigned int u32;

__device__ inline unsigned short f2bf(float f) {
  unsigned u = __float_as_uint(f);
  u += 0x7fff + ((u >> 16) & 1);   // round-to-nearest-even
  return (unsigned short)(u >> 16);
}
__device__ inline unsigned pack2bf(float a, float b) {
  return ((unsigned)f2bf(b) << 16) | f2bf(a);
}
__device__ inline float fast_tanh(float x) {
  x = fminf(15.f, fmaxf(-15.f, x));
  float e = __expf(2.f * x);
  return (e - 1.f) * __builtin_amdgcn_rcpf(e + 1.f);
}
// async global->LDS, 16B per lane; LDS dest = uniform base + lane*16
__device__ inline void gl_lds16(const void* g, void* l) {
  __builtin_amdgcn_global_load_lds(
      (const __attribute__((address_space(1))) u32*)g,
      (__attribute__((address_space(3))) u32*)l, 16, 0, 0);
}

// K^T bf16 tiled [kb][a][k'], 16B-group swizzle baked: group g of row a at g^(a&3).
__global__ void prep_kt(const float* __restrict__ K,
                        unsigned short* __restrict__ khi) {
  int idx = blockIdx.x * 256 + threadIdx.x;   // h*256 + a
  int h = idx >> 8;
  int a = idx & 255;
  int kb = h >> 5, k = h & 31;
  int grp = k >> 3, sub = k & 7;
  khi[kb * 8192 + a * 32 + ((grp ^ (a & 3)) * 8) + sub] = f2bf(K[idx]);
}

// gp4[gc][b][a] = partial of w0 * sum_g genes[b,g]*Wg[g,a]; gc==0 adds biases.
__global__ __launch_bounds__(256) void gene_proj_k(
    const float* __restrict__ genes, const float* __restrict__ w0p,
    const float* __restrict__ Wg, const float* __restrict__ bg,
    const float* __restrict__ db, float* __restrict__ gp4) {
  __shared__ float sg[532];
  int b = blockIdx.x;
  int gc = blockIdx.y;          // 0..3 chunks of 532
  int a = threadIdx.x;
  int g0 = gc * 532;
  for (int i = threadIdx.x; i < 532; i += 256) sg[i] = genes[(size_t)b * G_ + g0 + i];
  __syncthreads();
  float s = 0.f;
  #pragma unroll 8
  for (int g = 0; g < 532; ++g)
    s = fmaf(sg[g], Wg[(size_t)(g0 + g) * A_ + a], s);
  float val = w0p[0] * s;
  if (gc == 0) val += bg[a] + db[a];
  gp4[(gc * B_ + b) * A_ + a] = val;
}

// Fused: per (b, tb) tile of 128 t-rows:
//   phase A: GEMM xv[t] = sum_a v_a*tanh(gene_proj + smiles@K) (pass1 body)
//   phase B: LOCAL softmax partial: m = max_t xv, l = sum e^{xv-m}, p=e^{xv-m}
//   phase C: PV partial: outp[tb][h] = sum_t p[t]*smiles[b,t,h]  (fp32, L2/L3 re-read)
// Writes raw xv (for alphas), (m,l) per tile, unnormalized outp.
// No smb copy, no HBM stores in the K-loop.
// K-loop vm ledger/iter: [gl_lds16 x4][A-prefetch x4] -> s_waitcnt vmcnt(4)
// retires exactly the gl_lds16; prefetch stays in flight across the barrier.
__global__ __launch_bounds__(256, 2) void fused1(
    const float* __restrict__ smiles, const unsigned short* __restrict__ khi,
    const float* __restrict__ gp4, const float* __restrict__ v,
    float* __restrict__ xv, float* __restrict__ ml, float* __restrict__ outp) {
  __shared__ unsigned short sA[128 * 32];   // 8 KB
  __shared__ unsigned short sB[256 * 32];   // 16 KB
  __shared__ float sXV[128 * 4];            // 2 KB
  __shared__ float sP[128];
  __shared__ float sRed[8];

  const int tid = threadIdx.x;
  const int b = blockIdx.y;
  const int tb = blockIdx.x;                // 0..7 (128-t tiles)
  const int lane = tid & 63;
  const int w = tid >> 6;
  const int n = lane & 15;
  const int q = lane >> 4;

  // A staging: thread -> row ar (0..127), half-row (16 fp32)
  const int ar = tid >> 1;
  const int half = tid & 1;
  const int g0 = half * 2;                  // groups {0,1} or {2,3}
  const int s0 = (g0 ^ (ar & 3)) * 8;
  const int s1 = ((g0 + 1) ^ (ar & 3)) * 8;
  const float* asrc = smiles + ((size_t)(b * 1024 + tb * 128 + ar)) * 512 + half * 16;

  f32x4 acc[8][4];
  #pragma unroll
  for (int i = 0; i < 8; ++i)
    #pragma unroll
    for (int j = 0; j < 4; ++j)
      acc[i][j] = (f32x4){0.f, 0.f, 0.f, 0.f};

  float4 f0 = *reinterpret_cast<const float4*>(asrc);
  float4 f1 = *reinterpret_cast<const float4*>(asrc + 4);
  float4 f2 = *reinterpret_cast<const float4*>(asrc + 8);
  float4 f3 = *reinterpret_cast<const float4*>(asrc + 12);

  for (int kb = 0; kb < 16; ++kb) {
    // entry barrier: all waves consumed prev frags -> LDS safe to overwrite
    __builtin_amdgcn_sched_barrier(0);
    __builtin_amdgcn_s_barrier();
    __builtin_amdgcn_sched_barrier(0);

    // pack current A chunk (f regs from prev-iter prefetch)
    uint4 p0, p1;
    p0.x = pack2bf(f0.x, f0.y); p0.y = pack2bf(f0.z, f0.w);
    p0.z = pack2bf(f1.x, f1.y); p0.w = pack2bf(f1.z, f1.w);
    p1.x = pack2bf(f2.x, f2.y); p1.y = pack2bf(f2.z, f2.w);
    p1.z = pack2bf(f3.x, f3.y); p1.w = pack2bf(f3.z, f3.w);
    *reinterpret_cast<uint4*>(&sA[ar * 32 + s0]) = p0;    // ds_write (lgkm)
    *reinterpret_cast<uint4*>(&sA[ar * 32 + s1]) = p1;
    __builtin_amdgcn_sched_barrier(0);
    // vm ops 1-4: B stage
    #pragma unroll
    for (int r = 0; r < 4; ++r)
      gl_lds16(khi + kb * 8192 + w * 2048 + r * 512 + lane * 8,
               &sB[w * 2048 + r * 512]);
    __builtin_amdgcn_sched_barrier(0);
    // vm ops 5-8: prefetch next A chunk (clamped; last iter re-reads chunk 0)
    {
      int noff = (kb < 15) ? (kb + 1) * 32 : 0;
      f0 = *reinterpret_cast<const float4*>(asrc + noff);
      f1 = *reinterpret_cast<const float4*>(asrc + noff + 4);
      f2 = *reinterpret_cast<const float4*>(asrc + noff + 8);
      f3 = *reinterpret_cast<const float4*>(asrc + noff + 12);
    }
    // wait: sA ds_writes visible + the 4 gl_lds16 landed; the 4 prefetch
    // loads stay in flight across the barrier (complete under MFMAs).
    asm volatile("s_waitcnt vmcnt(4) lgkmcnt(0)" ::: "memory");
    __builtin_amdgcn_sched_barrier(0);
    __builtin_amdgcn_s_barrier();
    __builtin_amdgcn_sched_barrier(0);

    s16x8 af[8], bh[4];
    const int sw = (q ^ (n & 3)) * 8;
    #pragma unroll
    for (int j = 0; j < 4; ++j)
      bh[j] = *reinterpret_cast<const s16x8*>(&sB[(w * 64 + j * 16 + n) * 32 + sw]);
    #pragma unroll
    for (int i = 0; i < 8; ++i)
      af[i] = *reinterpret_cast<const s16x8*>(&sA[(i * 16 + n) * 32 + sw]);
    #pragma unroll
    for (int i = 0; i < 8; ++i)
      #pragma unroll
      for (int j = 0; j < 4; ++j)
        acc[i][j] = __builtin_amdgcn_mfma_f32_16x16x32_bf16(af[i], bh[j], acc[i][j], 0, 0, 0);
  }

  // epilogue: sum_a v_a * tanh(gp + proj); D: t = q*4+r (+16i), a = n (+16j+64w)
  float vv[4], gg[4];
  #pragma unroll
  for (int j = 0; j < 4; ++j) {
    int a = w * 64 + j * 16 + n;
    int idx = b * A_ + a;
    vv[j] = v[a];
    gg[j] = gp4[idx] + gp4[B_ * A_ + idx] + gp4[2 * B_ * A_ + idx] +
            gp4[3 * B_ * A_ + idx];
  }
  #pragma unroll
  for (int i = 0; i < 8; ++i) {
    #pragma unroll
    for (int r = 0; r < 4; ++r) {
      float s = 0.f;
      #pragma unroll
      for (int j = 0; j < 4; ++j)
        s += vv[j] * fast_tanh(acc[i][j][r] + gg[j]);
      s += __shfl_xor(s, 1); s += __shfl_xor(s, 2);
      s += __shfl_xor(s, 4); s += __shfl_xor(s, 8);
      if (n == 0) sXV[(i * 16 + q * 4 + r) * 4 + w] = s;
    }
  }
  __syncthreads();

  // phase B: local softmax partial over this tile's 128 xv values
  float xvv = -1e30f;
  if (tid < 128) {
    float* p = &sXV[tid * 4];
    xvv = p[0] + p[1] + p[2] + p[3];
    xv[(size_t)b * T_ + tb * 128 + tid] = xvv;      // raw, for final alphas
  }
  float mx = xvv;
  #pragma unroll
  for (int o = 1; o < 64; o <<= 1) mx = fmaxf(mx, __shfl_xor(mx, o));
  if (lane == 0) sRed[w] = mx;
  __syncthreads();
  mx = fmaxf(fmaxf(sRed[0], sRed[1]), fmaxf(sRed[2], sRed[3]));
  float e = (tid < 128) ? __expf(xvv - mx) : 0.f;
  float lsum = e;
  #pragma unroll
  for (int o = 1; o < 64; o <<= 1) lsum += __shfl_xor(lsum, o);
  if (lane == 0) sRed[4 + w] = lsum;
  if (tid < 128) sP[tid] = e;
  __syncthreads();
  if (tid == 0) {
    float l = sRed[4] + sRed[5] + sRed[6] + sRed[7];
    ml[(b * 8 + tb) * 2] = mx;
    ml[(b * 8 + tb) * 2 + 1] = l;
  }

  // phase C: outp[h] = sum_t p[t] * smiles[b, tile_t, h]; 2 h-cols per thread.
  // smiles slice (256 KB) was just streamed in phase A -> L2/L3-hot.
  float2 a2 = {0.f, 0.f};
  const float* sm2 = smiles + ((size_t)(b * 1024 + tb * 128)) * 512 + tid * 2;
  #pragma unroll 8
  for (int t = 0; t < 128; ++t) {
    float a = sP[t];
    float2 sv = *reinterpret_cast<const float2*>(sm2 + (size_t)t * 512);
    a2.x = fmaf(a, sv.x, a2.x);
    a2.y = fmaf(a, sv.y, a2.y);
  }
  *reinterpret_cast<float2*>(outp + ((size_t)(b * 8 + tb)) * 512 + tid * 2) = a2;
}

// merge: per b combine 8 tile partials (log-sum-exp), write out + alphas.
__global__ __launch_bounds__(256) void merge_k(
    const float* __restrict__ ml, const float* __restrict__ outp,
    const float* __restrict__ xv, float* __restrict__ out,
    float* __restrict__ alphas) {
  int b = blockIdx.x, tid = threadIdx.x;
  float m[8], lq[8];
  float M = -1e30f;
  #pragma unroll
  for (int q = 0; q < 8; ++q) {
    m[q] = ml[(b * 8 + q) * 2];
    lq[q] = ml[(b * 8 + q) * 2 + 1];
    M = fmaxf(M, m[q]);
  }
  float L = 0.f, wq[8];
  #pragma unroll
  for (int q = 0; q < 8; ++q) {
    wq[q] = __expf(m[q] - M);
    L = fmaf(lq[q], wq[q], L);
  }
  float invL = 1.f / L;
  float2 o2 = {0.f, 0.f};
  #pragma unroll
  for (int q = 0; q < 8; ++q) {
    float2 p = *reinterpret_cast<const float2*>(outp + ((size_t)(b * 8 + q)) * 512 + tid * 2);
    o2.x = fmaf(wq[q], p.x, o2.x);
    o2.y = fmaf(wq[q], p.y, o2.y);
  }
  o2.x *= invL; o2.y *= invL;
  *reinterpret_cast<float2*>(out + (size_t)b * H_ + tid * 2) = o2;
  #pragma unroll
  for (int t = tid; t < T_; t += 256)
    alphas[(size_t)b * T_ + t] = __expf(xv[(size_t)b * T_ + t] - M) * invL;
}

extern "C" void kernel_launch(void* const* d_in, const int* in_sizes, int n_in,
                              void* d_out, int out_size, void* d_ws, size_t ws_size,
                              hipStream_t stream) {
  const float* genes  = (const float*)d_in[0];
  const float* smiles = (const float*)d_in[1];
  const float* w0     = (const float*)d_in[2];
  const float* wg     = (const float*)d_in[3];
  const float* bg     = (const float*)d_in[4];
  const float* dk     = (const float*)d_in[5];
  const float* db     = (const float*)d_in[6];
  const float* v      = (const float*)d_in[7];
  float* out = (float*)d_out;            // [B,H] output then [B,T] alphas
  char* ws = (char*)d_ws;
  float* gp4 = (float*)ws;                                   // 512 KB (4 partials)
  unsigned short* khi = (unsigned short*)(ws + 524288);      // 256 KB
  float* xv   = (float*)(ws + 786432);                       // 512 KB raw energies
  float* ml   = (float*)(ws + 1310720);                      // 8 KB (m,l per tile)
  float* outp = (float*)(ws + 1318912);                      // 2 MB partial outputs
  float* alphas = out + B_ * H_;

  prep_kt<<<512, 256, 0, stream>>>(dk, khi);
  gene_proj_k<<<dim3(B_, 4), 256, 0, stream>>>(genes, w0, wg, bg, db, gp4);
  fused1<<<dim3(8, B_), 256, 0, stream>>>(smiles, khi, gp4, v, xv, ml, outp);
  merge_k<<<B_, 256, 0, stream>>>(ml, outp, xv, out, alphas);
}

// Round 4
// 476.167 us; speedup vs baseline: 1.0524x; 1.0205x over previous
//
#include <hip/hip_runtime.h>
#include <stdint.h>

#define B_ 128
#define T_ 1024
#define H_ 512
#define A_ 256
#define G_ 2128

typedef short s16x8 __attribute__((ext_vector_type(8)));
typedef float f32x4 __attribute__((ext_vector_type(4)));
typedef unsigned int u32;

__device__ inline unsigned short f2bf(float f) {
  unsigned u = __float_as_uint(f);
  u += 0x7fff + ((u >> 16) & 1);   // round-to-nearest-even
  return (unsigned short)(u >> 16);
}
__device__ inline unsigned pack2bf(float a, float b) {
  return ((unsigned)f2bf(b) << 16) | f2bf(a);
}
__device__ inline float fast_tanh(float x) {
  x = fminf(15.f, fmaxf(-15.f, x));
  float e = __expf(2.f * x);
  return (e - 1.f) * __builtin_amdgcn_rcpf(e + 1.f);
}
// async global->LDS, 16B per lane; LDS dest = uniform base + lane*16
__device__ inline void gl_lds16(const void* g, void* l) {
  __builtin_amdgcn_global_load_lds(
      (const __attribute__((address_space(1))) u32*)g,
      (__attribute__((address_space(3))) u32*)l, 16, 0, 0);
}

// K^T bf16 tiled [kb][a][k'], 16B-group swizzle baked: group g of row a at g^(a&3).
__global__ void prep_kt(const float* __restrict__ K,
                        unsigned short* __restrict__ khi) {
  int idx = blockIdx.x * 256 + threadIdx.x;   // h*256 + a
  int h = idx >> 8;
  int a = idx & 255;
  int kb = h >> 5, k = h & 31;
  int grp = k >> 3, sub = k & 7;
  khi[kb * 8192 + a * 32 + ((grp ^ (a & 3)) * 8) + sub] = f2bf(K[idx]);
}

// gp4[gc][b][a] = partial of w0 * sum_g genes[b,g]*Wg[g,a]; gc==0 adds biases.
__global__ __launch_bounds__(256) void gene_proj_k(
    const float* __restrict__ genes, const float* __restrict__ w0p,
    const float* __restrict__ Wg, const float* __restrict__ bg,
    const float* __restrict__ db, float* __restrict__ gp4) {
  __shared__ float sg[532];
  int b = blockIdx.x;
  int gc = blockIdx.y;          // 0..3 chunks of 532
  int a = threadIdx.x;
  int g0 = gc * 532;
  for (int i = threadIdx.x; i < 532; i += 256) sg[i] = genes[(size_t)b * G_ + g0 + i];
  __syncthreads();
  float s = 0.f;
  #pragma unroll 8
  for (int g = 0; g < 532; ++g)
    s = fmaf(sg[g], Wg[(size_t)(g0 + g) * A_ + a], s);
  float val = w0p[0] * s;
  if (gc == 0) val += bg[a] + db[a];
  gp4[(gc * B_ + b) * A_ + a] = val;
}

// Fused, 64-row tiles (m97-shape per wave: 4x4 16x16x32 frags, ~150 VGPR,
// target 3 blocks/CU). Per (b, tb in 0..15):
//   phase A: GEMM proj = smiles_tile @ K  (64t x 256a), K=512 in 16 steps
//   phase B: xv = sum_a v*tanh(gp+proj); local softmax partial (m,l,p)
//   phase C: outp[tb][h] = sum_t p[t]*smiles[t,h] (fp32 re-read, L2/L3-hot)
// K-loop vm ledger/iter: [gl_lds16 x4][A-prefetch x2] -> s_waitcnt vmcnt(2)
// retires exactly the gl_lds16; the 2 prefetches fly across the barrier.
__global__ __launch_bounds__(256, 3) void fused1(
    const float* __restrict__ smiles, const unsigned short* __restrict__ khi,
    const float* __restrict__ gp4, const float* __restrict__ v,
    float* __restrict__ xv, float* __restrict__ ml, float* __restrict__ outp) {
  __shared__ unsigned short sA[64 * 32];    // 4 KB
  __shared__ unsigned short sB[256 * 32];   // 16 KB
  __shared__ float sXV[64 * 4];             // 1 KB
  __shared__ float sP[64];

  const int tid = threadIdx.x;
  const int b = blockIdx.y;
  const int tb = blockIdx.x;                // 0..15 (64-t tiles)
  const int lane = tid & 63;
  const int w = tid >> 6;
  const int n = lane & 15;
  const int q = lane >> 4;

  // A staging: thread -> row ar (0..63), 8-float group g8 (0..3)
  const int ar = tid >> 2;
  const int g8 = tid & 3;
  const int s0 = (g8 ^ (ar & 3)) * 8;       // swizzled 16B-group slot
  const float* asrc = smiles + ((size_t)(b * 1024 + tb * 64 + ar)) * 512 + g8 * 8;

  f32x4 acc[4][4];
  #pragma unroll
  for (int i = 0; i < 4; ++i)
    #pragma unroll
    for (int j = 0; j < 4; ++j)
      acc[i][j] = (f32x4){0.f, 0.f, 0.f, 0.f};

  float4 f0 = *reinterpret_cast<const float4*>(asrc);
  float4 f1 = *reinterpret_cast<const float4*>(asrc + 4);

  for (int kb = 0; kb < 16; ++kb) {
    // entry barrier: all waves consumed prev frags -> LDS safe to overwrite
    __builtin_amdgcn_sched_barrier(0);
    __builtin_amdgcn_s_barrier();
    __builtin_amdgcn_sched_barrier(0);

    // pack current A chunk (f regs from prev-iter prefetch)
    uint4 p0;
    p0.x = pack2bf(f0.x, f0.y); p0.y = pack2bf(f0.z, f0.w);
    p0.z = pack2bf(f1.x, f1.y); p0.w = pack2bf(f1.z, f1.w);
    *reinterpret_cast<uint4*>(&sA[ar * 32 + s0]) = p0;    // ds_write (lgkm)
    __builtin_amdgcn_sched_barrier(0);
    // vm ops 1-4: B stage
    #pragma unroll
    for (int r = 0; r < 4; ++r)
      gl_lds16(khi + kb * 8192 + w * 2048 + r * 512 + lane * 8,
               &sB[w * 2048 + r * 512]);
    __builtin_amdgcn_sched_barrier(0);
    // vm ops 5-6: prefetch next A chunk (clamped; last iter re-reads chunk 0)
    {
      int noff = (kb < 15) ? (kb + 1) * 32 : 0;
      f0 = *reinterpret_cast<const float4*>(asrc + noff);
      f1 = *reinterpret_cast<const float4*>(asrc + noff + 4);
    }
    // wait: sA ds_write visible + the 4 gl_lds16 landed; the 2 prefetch
    // loads stay in flight across the barrier (complete under MFMAs).
    asm volatile("s_waitcnt vmcnt(2) lgkmcnt(0)" ::: "memory");
    __builtin_amdgcn_sched_barrier(0);
    __builtin_amdgcn_s_barrier();
    __builtin_amdgcn_sched_barrier(0);

    s16x8 af[4], bh[4];
    const int sw = (q ^ (n & 3)) * 8;
    #pragma unroll
    for (int j = 0; j < 4; ++j)
      bh[j] = *reinterpret_cast<const s16x8*>(&sB[(w * 64 + j * 16 + n) * 32 + sw]);
    #pragma unroll
    for (int i = 0; i < 4; ++i)
      af[i] = *reinterpret_cast<const s16x8*>(&sA[(i * 16 + n) * 32 + sw]);
    #pragma unroll
    for (int i = 0; i < 4; ++i)
      #pragma unroll
      for (int j = 0; j < 4; ++j)
        acc[i][j] = __builtin_amdgcn_mfma_f32_16x16x32_bf16(af[i], bh[j], acc[i][j], 0, 0, 0);
  }

  // epilogue: sum_a v_a * tanh(gp + proj); D: t = i*16 + q*4+r, a = w*64+j*16+n
  float vv[4], gg[4];
  #pragma unroll
  for (int j = 0; j < 4; ++j) {
    int a = w * 64 + j * 16 + n;
    int idx = b * A_ + a;
    vv[j] = v[a];
    gg[j] = gp4[idx] + gp4[B_ * A_ + idx] + gp4[2 * B_ * A_ + idx] +
            gp4[3 * B_ * A_ + idx];
  }
  #pragma unroll
  for (int i = 0; i < 4; ++i) {
    #pragma unroll
    for (int r = 0; r < 4; ++r) {
      float s = 0.f;
      #pragma unroll
      for (int j = 0; j < 4; ++j)
        s += vv[j] * fast_tanh(acc[i][j][r] + gg[j]);
      s += __shfl_xor(s, 1); s += __shfl_xor(s, 2);
      s += __shfl_xor(s, 4); s += __shfl_xor(s, 8);
      if (n == 0) sXV[(i * 16 + q * 4 + r) * 4 + w] = s;
    }
  }
  __syncthreads();

  // phase B: wave 0 owns the tile's 64 xv values; local softmax partial
  if (w == 0) {
    float* p = &sXV[lane * 4];
    float xvv = p[0] + p[1] + p[2] + p[3];
    xv[(size_t)b * T_ + tb * 64 + lane] = xvv;     // raw, for final alphas
    float mx = xvv;
    #pragma unroll
    for (int o = 1; o < 64; o <<= 1) mx = fmaxf(mx, __shfl_xor(mx, o));
    float e = __expf(xvv - mx);
    sP[lane] = e;
    float lsum = e;
    #pragma unroll
    for (int o = 1; o < 64; o <<= 1) lsum += __shfl_xor(lsum, o);
    if (lane == 0) {
      ml[(b * 16 + tb) * 2] = mx;
      ml[(b * 16 + tb) * 2 + 1] = lsum;
    }
  }
  __syncthreads();

  // phase C: outp[h] = sum_t p[t] * smiles[b, tile_t, h]; 2 h-cols per thread.
  float2 a2 = {0.f, 0.f};
  const float* sm2 = smiles + ((size_t)(b * 1024 + tb * 64)) * 512 + tid * 2;
  #pragma unroll 8
  for (int t = 0; t < 64; ++t) {
    float a = sP[t];
    float2 sv = *reinterpret_cast<const float2*>(sm2 + (size_t)t * 512);
    a2.x = fmaf(a, sv.x, a2.x);
    a2.y = fmaf(a, sv.y, a2.y);
  }
  *reinterpret_cast<float2*>(outp + ((size_t)(b * 16 + tb)) * 512 + tid * 2) = a2;
}

// merge: per b combine 16 tile partials (log-sum-exp), write out + alphas.
__global__ __launch_bounds__(256) void merge_k(
    const float* __restrict__ ml, const float* __restrict__ outp,
    const float* __restrict__ xv, float* __restrict__ out,
    float* __restrict__ alphas) {
  int b = blockIdx.x, tid = threadIdx.x;
  float m[16], lq[16];
  float M = -1e30f;
  #pragma unroll
  for (int t = 0; t < 16; ++t) {
    m[t] = ml[(b * 16 + t) * 2];
    lq[t] = ml[(b * 16 + t) * 2 + 1];
    M = fmaxf(M, m[t]);
  }
  float L = 0.f, wq[16];
  #pragma unroll
  for (int t = 0; t < 16; ++t) {
    wq[t] = __expf(m[t] - M);
    L = fmaf(lq[t], wq[t], L);
  }
  float invL = 1.f / L;
  float2 o2 = {0.f, 0.f};
  #pragma unroll
  for (int t = 0; t < 16; ++t) {
    float2 p = *reinterpret_cast<const float2*>(outp + ((size_t)(b * 16 + t)) * 512 + tid * 2);
    o2.x = fmaf(wq[t], p.x, o2.x);
    o2.y = fmaf(wq[t], p.y, o2.y);
  }
  o2.x *= invL; o2.y *= invL;
  *reinterpret_cast<float2*>(out + (size_t)b * H_ + tid * 2) = o2;
  #pragma unroll
  for (int t = tid; t < T_; t += 256)
    alphas[(size_t)b * T_ + t] = __expf(xv[(size_t)b * T_ + t] - M) * invL;
}

extern "C" void kernel_launch(void* const* d_in, const int* in_sizes, int n_in,
                              void* d_out, int out_size, void* d_ws, size_t ws_size,
                              hipStream_t stream) {
  const float* genes  = (const float*)d_in[0];
  const float* smiles = (const float*)d_in[1];
  const float* w0     = (const float*)d_in[2];
  const float* wg     = (const float*)d_in[3];
  const float* bg     = (const float*)d_in[4];
  const float* dk     = (const float*)d_in[5];
  const float* db     = (const float*)d_in[6];
  const float* v      = (const float*)d_in[7];
  float* out = (float*)d_out;            // [B,H] output then [B,T] alphas
  char* ws = (char*)d_ws;
  float* gp4 = (float*)ws;                                   // 512 KB (4 partials)
  unsigned short* khi = (unsigned short*)(ws + 524288);      // 256 KB
  float* xv   = (float*)(ws + 786432);                       // 512 KB raw energies
  float* ml   = (float*)(ws + 1310720);                      // 16 KB (m,l per tile)
  float* outp = (float*)(ws + 1327104);                      // 4 MB partial outputs
  float* alphas = out + B_ * H_;

  prep_kt<<<512, 256, 0, stream>>>(dk, khi);
  gene_proj_k<<<dim3(B_, 4), 256, 0, stream>>>(genes, w0, wg, bg, db, gp4);
  fused1<<<dim3(16, B_), 256, 0, stream>>>(smiles, khi, gp4, v, xv, ml, outp);
  merge_k<<<B_, 256, 0, stream>>>(ml, outp, xv, out, alphas);
}